// Round 1
// baseline (1324.962 us; speedup 1.0000x reference)
//
#include <hip/hip_runtime.h>

#define N 20000
#define K 20
#define T 50
#define D 200
#define NB 8           // n's per block
#define THREADS 256
#define STRT 164       // theta_t LDS stride per t (dwords): 20*8=160 + 4 pad (keeps 16B align)

// d_out layout: pi [N*D*T] | theta [N*K*T] | phi_prob [K*D*T]
#define TH_OFF 200000000
#define PH_OFF 220000000

__global__ __launch_bounds__(256) void sigmoid_kernel(const float* __restrict__ phi,
                                                      float* __restrict__ out) {
    int idx = blockIdx.x * 256 + threadIdx.x;
    if (idx < K * D * T) {
        float x = phi[idx];
        out[idx] = 1.0f / (1.0f + __expf(-x));
    }
}

__global__ __launch_bounds__(THREADS, 4) void fused_kernel(
    const float* __restrict__ lambda_, const float* __restrict__ phi_prob,
    float* __restrict__ pi_out, float* __restrict__ theta_out) {
    __shared__ __align__(16) float theta_t[T * STRT];
    const int n0 = blockIdx.x * NB;
    const int tid = threadIdx.x;

    // ---- Phase 1: softmax over K for all (i, t) pairs of this block ----
    // lambda is read-once: non-temporal loads keep it out of L2.
    // theta is write-once streaming: non-temporal stores avoid L2 write-allocate.
    for (int p = tid; p < NB * T; p += THREADS) {
        const int t = p % T;
        const int i = p / T;
        const float* lp = lambda_ + (n0 + i) * (K * T) + t;
        float v[K];
#pragma unroll
        for (int k = 0; k < K; ++k) v[k] = __builtin_nontemporal_load(lp + k * T);
        float m = v[0];
#pragma unroll
        for (int k = 1; k < K; ++k) m = fmaxf(m, v[k]);
        float s = 0.f;
#pragma unroll
        for (int k = 0; k < K; ++k) { v[k] = __expf(v[k] - m); s += v[k]; }
        const float inv = 1.0f / s;
        float* to = theta_out + (n0 + i) * (K * T) + t;
#pragma unroll
        for (int k = 0; k < K; ++k) {
            const float th = v[k] * inv;
            theta_t[t * STRT + k * NB + i] = th;
            __builtin_nontemporal_store(th, to + k * T);
        }
    }
    __syncthreads();

    // ---- Phase 2: pi[n0:n0+8, :, :] = theta @ phi_prob, 8n x 8d register tile ----
    // phi_prob loads stay CACHED (the whole point: 800 KB must remain L2-resident).
    // pi stores are non-temporal: 800 MB of streaming writes must not evict phi.
    const int NTASK = T * (D / 8);  // 1250 tasks: (t, d-octet)
    for (int task = tid; task < NTASK; task += THREADS) {
        const int t = task % T;
        const int dblk = task / T;
        const float* pp = phi_prob + dblk * 8 * T + t;
        const float* th_base = theta_t + t * STRT;
        float acc[NB][8];
#pragma unroll
        for (int i = 0; i < NB; ++i)
#pragma unroll
            for (int j = 0; j < 8; ++j) acc[i][j] = 0.f;

#pragma unroll 2
        for (int k = 0; k < K; ++k) {
            float ph[8];
#pragma unroll
            for (int j = 0; j < 8; ++j) ph[j] = pp[k * (D * T) + j * T];
            const float4 th0 = *(const float4*)(th_base + k * NB);
            const float4 th1 = *(const float4*)(th_base + k * NB + 4);
            float th[8] = {th0.x, th0.y, th0.z, th0.w, th1.x, th1.y, th1.z, th1.w};
#pragma unroll
            for (int i = 0; i < NB; ++i)
#pragma unroll
                for (int j = 0; j < 8; ++j)
                    acc[i][j] = fmaf(th[i], ph[j], acc[i][j]);
        }

        float* op = pi_out + (size_t)n0 * (D * T) + dblk * 8 * T + t;
#pragma unroll
        for (int i = 0; i < NB; ++i) {
#pragma unroll
            for (int j = 0; j < 8; ++j) {
                float x = acc[i][j];
                x = fmaxf(x, 1e-8f);
                x = fminf(x, 0.99999994f);  // float32(1.0 - 1e-8)
                __builtin_nontemporal_store(x, op + i * (D * T) + j * T);
            }
        }
    }
}

extern "C" void kernel_launch(void* const* d_in, const int* in_sizes, int n_in,
                              void* d_out, int out_size, void* d_ws, size_t ws_size,
                              hipStream_t stream) {
    const float* lambda_ = (const float*)d_in[0];
    const float* phi = (const float*)d_in[1];
    float* out = (float*)d_out;
    float* pi_out = out;
    float* theta_out = out + TH_OFF;
    float* phi_out = out + PH_OFF;

    sigmoid_kernel<<<(K * D * T + 255) / 256, 256, 0, stream>>>(phi, phi_out);
    fused_kernel<<<N / NB, THREADS, 0, stream>>>(lambda_, phi_out, pi_out, theta_out);
}

// Round 3
// 1071.768 us; speedup vs baseline: 1.2362x; 1.2362x over previous
//
#include <hip/hip_runtime.h>

#define N 20000
#define K 20
#define T 50
#define D 200
#define NB 16          // n's per block
#define THREADS 512
#define STRT 324       // theta_t LDS stride per t (dwords): 20*16=320 + 4 pad; 324%32=4 keeps
                       // the 2-way-free bank rotation and 16B alignment. 50*324*4 = 64800 B.

// d_out layout: pi [N*D*T] | theta [N*K*T] | phi_prob [K*D*T]
#define TH_OFF 200000000
#define PH_OFF 220000000

__global__ __launch_bounds__(256) void sigmoid_kernel(const float* __restrict__ phi,
                                                      float* __restrict__ out) {
    int idx = blockIdx.x * 256 + threadIdx.x;
    if (idx < K * D * T) {
        float x = phi[idx];
        out[idx] = 1.0f / (1.0f + __expf(-x));
    }
}

__global__ __launch_bounds__(THREADS, 4) void fused_kernel(
    const float* __restrict__ lambda_, const float* __restrict__ phi_prob,
    float* __restrict__ pi_out, float* __restrict__ theta_out) {
    __shared__ __align__(16) float theta_t[T * STRT];  // 64800 B
    const int n0 = blockIdx.x * NB;
    const int tid = threadIdx.x;

    // ---- Phase 1: softmax over K for all (i, t) pairs of this block ----
    // Cached (normal) loads/stores: L2 merges the 200B-chunk theta stores into full lines.
    for (int p = tid; p < NB * T; p += THREADS) {
        const int t = p % T;
        const int i = p / T;
        const float* lp = lambda_ + (n0 + i) * (K * T) + t;
        float v[K];
#pragma unroll
        for (int k = 0; k < K; ++k) v[k] = lp[k * T];
        float m = v[0];
#pragma unroll
        for (int k = 1; k < K; ++k) m = fmaxf(m, v[k]);
        float s = 0.f;
#pragma unroll
        for (int k = 0; k < K; ++k) { v[k] = __expf(v[k] - m); s += v[k]; }
        const float inv = 1.0f / s;
        float* to = theta_out + (n0 + i) * (K * T) + t;
#pragma unroll
        for (int k = 0; k < K; ++k) {
            const float th = v[k] * inv;
            theta_t[t * STRT + k * NB + i] = th;
            to[k * T] = th;
        }
    }
    __syncthreads();

    // ---- Phase 2: pi[n0:n0+16, :, :] = theta @ phi_prob, 16n x 4d register tile ----
    // 64 FMA per 4 phi loads (16:1) — half the VMEM instruction count of the 8x8 tile,
    // and each block streams phi exactly once (1250 blocks -> 1 TB aggregate L2 phi reads).
    const int NTASK = T * (D / 4);  // 2500 tasks: (t, d-quad)
    for (int task = tid; task < NTASK; task += THREADS) {
        const int t = task % T;
        const int dq = task / T;
        const float* pp = phi_prob + dq * 4 * T + t;
        const float* th_base = theta_t + t * STRT;
        float acc[NB][4];
#pragma unroll
        for (int i = 0; i < NB; ++i)
#pragma unroll
            for (int j = 0; j < 4; ++j) acc[i][j] = 0.f;

#pragma unroll 2
        for (int k = 0; k < K; ++k) {
            float ph[4];
#pragma unroll
            for (int j = 0; j < 4; ++j) ph[j] = pp[k * (D * T) + j * T];
            const float4 th0 = *(const float4*)(th_base + k * NB);
            const float4 th1 = *(const float4*)(th_base + k * NB + 4);
            const float4 th2 = *(const float4*)(th_base + k * NB + 8);
            const float4 th3 = *(const float4*)(th_base + k * NB + 12);
            float th[NB] = {th0.x, th0.y, th0.z, th0.w, th1.x, th1.y, th1.z, th1.w,
                            th2.x, th2.y, th2.z, th2.w, th3.x, th3.y, th3.z, th3.w};
#pragma unroll
            for (int i = 0; i < NB; ++i)
#pragma unroll
                for (int j = 0; j < 4; ++j)
                    acc[i][j] = fmaf(th[i], ph[j], acc[i][j]);
        }

        float* op = pi_out + (size_t)n0 * (D * T) + dq * 4 * T + t;
#pragma unroll
        for (int i = 0; i < NB; ++i) {
#pragma unroll
            for (int j = 0; j < 4; ++j) {
                float x = acc[i][j];
                x = fmaxf(x, 1e-8f);
                x = fminf(x, 0.99999994f);  // float32(1.0 - 1e-8)
                op[i * (D * T) + j * T] = x;
            }
        }
    }
}

extern "C" void kernel_launch(void* const* d_in, const int* in_sizes, int n_in,
                              void* d_out, int out_size, void* d_ws, size_t ws_size,
                              hipStream_t stream) {
    const float* lambda_ = (const float*)d_in[0];
    const float* phi = (const float*)d_in[1];
    float* out = (float*)d_out;
    float* pi_out = out;
    float* theta_out = out + TH_OFF;
    float* phi_out = out + PH_OFF;

    sigmoid_kernel<<<(K * D * T + 255) / 256, 256, 0, stream>>>(phi, phi_out);
    fused_kernel<<<N / NB, THREADS, 0, stream>>>(lambda_, phi_out, pi_out, theta_out);
}